// Round 20
// baseline (338.602 us; speedup 1.0000x reference)
//
#include <hip/hip_runtime.h>
#include <hip/hip_bf16.h>
#include <hip/hip_fp16.h>

typedef _Float16 half_t;
typedef _Float16 half8 __attribute__((ext_vector_type(8)));
typedef _Float16 half4 __attribute__((ext_vector_type(4)));
typedef float f32x4 __attribute__((ext_vector_type(4)));

#define BB 8
#define SS 4096
#define DD 256
#define HH 8
#define LL 4
#define MTOT (BB*SS)   // 32768

__device__ inline float gelu_f(float v) { return 0.5f * v * (1.0f + erff(v * 0.70710678118f)); }
__device__ inline half8 splat8(half_t v) { return (half8){v, v, v, v, v, v, v, v}; }

// async global->LDS, 16B per lane; LDS dest linear in lane order.
__device__ __forceinline__ void gload16(const half_t* g, half_t* l) {
    __builtin_amdgcn_global_load_lds(
        (const __attribute__((address_space(1))) void*)g,
        (__attribute__((address_space(3))) void*)l, 16, 0, 0);
}

// ---------------- weight prep: fold LN gamma/beta into weights ----------------
__global__ __launch_bounds__(256) void prep_weights(
    const float* __restrict__ Wq, const float* __restrict__ Wk, const float* __restrict__ Wv,
    const float* __restrict__ W1, const float* __restrict__ b1,
    const float* __restrict__ W2, const float* __restrict__ b2,
    const float* __restrict__ gamma, const float* __restrict__ beta,
    half_t* __restrict__ Wall, half_t* __restrict__ W1h, half_t* __restrict__ W2h,
    float* __restrict__ bqkv, float* __restrict__ b1f, float* __restrict__ b2f)
{
    int blk = blockIdx.x;            // 20 blocks: l*5 + type
    int l = blk / 5, type = blk % 5;
    int o = threadIdx.x;
    const float* src = (type == 0 ? Wq : type == 1 ? Wk : type == 2 ? Wv : type == 3 ? W1 : W2)
                       + ((size_t)l * 256 + o) * 256;
    half_t* dsth = (type < 3) ? Wall + ((size_t)(l * 3 + type) * 256 + o) * 256
                 : (type == 3) ? W1h + ((size_t)l * 256 + o) * 256
                               : W2h + ((size_t)l * 256 + o) * 256;
    float acc = 0.f;
    for (int d4 = 0; d4 < 64; ++d4) {
        float4 w = *(const float4*)(src + d4 * 4);
        half4 hv;
        if (type == 4) {
            hv = half4{ (half_t)w.x, (half_t)w.y, (half_t)w.z, (half_t)w.w };
        } else {
            float4 g = *(const float4*)(gamma + d4 * 4);
            float4 bt = *(const float4*)(beta + d4 * 4);
            acc += w.x * bt.x + w.y * bt.y + w.z * bt.z + w.w * bt.w;
            hv = half4{ (half_t)(w.x * g.x), (half_t)(w.y * g.y), (half_t)(w.z * g.z), (half_t)(w.w * g.w) };
        }
        *(half4*)(dsth + d4 * 4) = hv;
    }
    if (type < 3) bqkv[(l * 3 + type) * 256 + o] = acc;
    else if (type == 3) b1f[l * 256 + o] = b1[l * 256 + o] + acc;
    else b2f[l * 256 + o] = b2[l * 256 + o];
}

// ---------------- x fp32 -> fp16 + raw row sums (partial-stats format) ----------------
__global__ __launch_bounds__(256) void cvt_x_stats(const float* __restrict__ in,
                                                   half_t* __restrict__ out,
                                                   float2* __restrict__ st0,
                                                   float2* __restrict__ st1) {
    int wave = threadIdx.x >> 6, lane = threadIdx.x & 63;
    int row = blockIdx.x * 4 + wave;
    const float* ip = in + (size_t)row * DD + lane * 4;
    float4 v = *(const float4*)ip;
    half4 h = { (half_t)v.x, (half_t)v.y, (half_t)v.z, (half_t)v.w };
    *(half4*)(out + (size_t)row * DD + lane * 4) = h;
    float s1 = v.x + v.y + v.z + v.w;
    float s2 = v.x * v.x + v.y * v.y + v.z * v.z + v.w * v.w;
    #pragma unroll
    for (int m = 32; m; m >>= 1) {
        s1 += __shfl_xor(s1, m);
        s2 += __shfl_xor(s2, m);
    }
    if (lane == 0) {
        st0[row] = make_float2(s1, s2);
        st1[row] = make_float2(0.f, 0.f);
    }
}

// ---------------- XCD-aware bijective remap (gridDim.x % 8 == 0) ----------------
__device__ inline void xcd_remap(int& bx, int& by, int& bz) {
    int lin = blockIdx.x + gridDim.x * (blockIdx.y + gridDim.y * blockIdx.z);
    int nyz = gridDim.y * gridDim.z;
    int xcd = lin & 7;
    int slot = lin >> 3;
    int yz = slot % nyz;
    int xi = slot / nyz;
    bx = xcd + 8 * xi;
    by = yz % gridDim.y;
    bz = yz / gridDim.y;
}

// ---------------- 64x128 GEMM: BM=64, single-buffer 24KB, 4 waves of 32x64 --------------
// Used for ALL GEMMs (QKV via grid.z=3). ~6 blocks/CU; latency hidden by TLP.
// C = LN?(A) @ W^T + bias; NORM combines partial sums st0+st1 -> (mu,rs) at frag read.
// EPI 0: store; 1: gelu; 2: gelu + resid. STATS: emit per-by-half partial row sums.
template<int NORM, int EPI, int STATS>
__global__ __launch_bounds__(256) void gemm64r(const half_t* __restrict__ A,
                                               const float2* __restrict__ st0,
                                               const float2* __restrict__ st1,
                                               const half_t* __restrict__ Wbase,
                                               const float* __restrict__ biasBase,
                                               const half_t* __restrict__ resid,
                                               half_t* __restrict__ o0,
                                               half_t* __restrict__ o1,
                                               half_t* __restrict__ o2,
                                               float2* __restrict__ outSt0,
                                               float2* __restrict__ outSt1) {
    const int t = threadIdx.x, lane = t & 63, wavei = t >> 6;
    const int wm = wavei >> 1, wn = wavei & 1, r = lane & 15, g = lane >> 4;
    int bx, by, bz;
    xcd_remap(bx, by, bz);
    const int row0 = bx * 64, col0 = by * 128;
    const half_t* W = Wbase + (size_t)bz * 65536;
    const float* bias = biasBase + bz * 256;
    half_t* outp = (bz == 0) ? o0 : ((bz == 1) ? o1 : o2);

    __shared__ __align__(16) half_t lds[12288];   // A [0,4096), W [4096,12288)

    const half_t* Ag = A + (size_t)row0 * DD;
    const half_t* Wg = W + (size_t)col0 * DD;

    half8 sA[2], bA[2];
    if (NORM) {
        #pragma unroll
        for (int mt = 0; mt < 2; ++mt) {
            int row = row0 + wm * 32 + mt * 16 + r;
            float2 p0 = st0[row], p1 = st1[row];
            float s1 = p0.x + p1.x, s2 = p0.y + p1.y;
            float mu = s1 * (1.0f / DD);
            float var = s2 * (1.0f / DD) - mu * mu;
            float rs = rsqrtf(var + 1e-5f);
            sA[mt] = splat8((half_t)rs);
            bA[mt] = splat8((half_t)(-mu * rs));
        }
    }

    int rwA[2], chA[2], rwW[4], chW[4];
    #pragma unroll
    for (int i = 0; i < 2; ++i) {
        int G = i * 256 + t;
        rwA[i] = G >> 3;
        chA[i] = ((G & 7) ^ (rwA[i] & 7)) * 8;
    }
    #pragma unroll
    for (int i = 0; i < 4; ++i) {
        int G = i * 256 + t;
        rwW[i] = G >> 3;
        chW[i] = ((G & 7) ^ (rwW[i] & 7)) * 8;
    }

    f32x4 acc[2][4];
    #pragma unroll
    for (int i = 0; i < 2; ++i)
        #pragma unroll
        for (int j = 0; j < 4; ++j) acc[i][j] = (f32x4){0.f, 0.f, 0.f, 0.f};

    #pragma unroll
    for (int stp = 0; stp < 4; ++stp) {
        int kk = stp * 64;
        #pragma unroll
        for (int i = 0; i < 2; ++i)
            gload16(Ag + (size_t)rwA[i] * DD + kk + chA[i], &lds[(i * 256 + t) * 8]);
        #pragma unroll
        for (int i = 0; i < 4; ++i)
            gload16(Wg + (size_t)rwW[i] * DD + kk + chW[i], &lds[4096 + (i * 256 + t) * 8]);
        __syncthreads();
        #pragma unroll
        for (int ks = 0; ks < 2; ++ks) {
            half8 af[2], bf[4];
            #pragma unroll
            for (int mt = 0; mt < 2; ++mt) {
                int rw = wm * 32 + mt * 16 + r;
                int cc = (ks * 4 + g) ^ (rw & 7);
                half8 raw = *(const half8*)&lds[rw * 64 + cc * 8];
                af[mt] = NORM ? (half8)(raw * sA[mt] + bA[mt]) : raw;
            }
            #pragma unroll
            for (int nt = 0; nt < 4; ++nt) {
                int rw = wn * 64 + nt * 16 + r;
                int cc = (ks * 4 + g) ^ (rw & 7);
                bf[nt] = *(const half8*)&lds[4096 + rw * 64 + cc * 8];
            }
            #pragma unroll
            for (int mt = 0; mt < 2; ++mt)
                #pragma unroll
                for (int nt = 0; nt < 4; ++nt)
                    acc[mt][nt] = __builtin_amdgcn_mfma_f32_16x16x32_f16(af[mt], bf[nt], acc[mt][nt], 0, 0, 0);
        }
        __syncthreads();
    }

    // epilogue: 64x128 tile (16KB) into lds[0..8191]
    half_t* ldsT = &lds[0];
    #pragma unroll
    for (int mt = 0; mt < 2; ++mt) {
        #pragma unroll
        for (int nt = 0; nt < 4; ++nt) {
            int colL = wn * 64 + nt * 16 + r;
            float bv = bias[col0 + colL];
            #pragma unroll
            for (int j = 0; j < 4; ++j) {
                int rowL = wm * 32 + mt * 16 + g * 4 + j;
                float v = acc[mt][nt][j] + bv;
                if (EPI != 0) v = gelu_f(v);
                ldsT[rowL * 128 + (colL ^ ((rowL & 12) << 2))] = (half_t)v;
            }
        }
    }
    __syncthreads();
    float2* outSt = (by == 0) ? outSt0 : outSt1;
    #pragma unroll
    for (int i = 0; i < 4; ++i) {
        int G = i * 256 + t;
        int rowL = G >> 4;
        int colL = (G & 15) * 8;
        half8 v = *(const half8*)&ldsT[rowL * 128 + (colL ^ ((rowL & 12) << 2))];
        size_t off = (size_t)(row0 + rowL) * DD + col0 + colL;
        if (EPI == 2) {
            half8 rsd = *(const half8*)&resid[off];
            #pragma unroll
            for (int q = 0; q < 8; ++q) v[q] = (half_t)((float)v[q] + (float)rsd[q]);
        }
        *(half8*)&outp[off] = v;
        if (STATS) {
            float s1 = 0.f, s2 = 0.f;
            #pragma unroll
            for (int q = 0; q < 8; ++q) { float f = (float)v[q]; s1 += f; s2 += f * f; }
            #pragma unroll
            for (int m = 1; m <= 8; m <<= 1) {
                s1 += __shfl_xor(s1, m);
                s2 += __shfl_xor(s2, m);
            }
            if ((t & 15) == 0) outSt[row0 + rowL] = make_float2(s1, s2);
        }
    }
}

// ---------------- diag: LDS-tiled ----------------
__global__ __launch_bounds__(256) void diag_tiled(const half_t* __restrict__ Q,
                                                  const half_t* __restrict__ K,
                                                  float* __restrict__ dg) {
    int blk = blockIdx.x;                 // b*128 + h*16 + sblk
    int sblk = blk & 15, h = (blk >> 4) & 7, b = blk >> 7;
    int t = threadIdx.x;
    __shared__ __align__(16) half_t kt[256 * 32];   // 16 KB
    int r0b = sblk * 8;
    {
        int e = t >> 3, del = t & 7;
        const half_t* kp = K + ((size_t)b * SS + e * 128 + r0b + del) * DD + h * 32;
        int4* dst = (int4*)&kt[t * 32];
        const int4* sp = (const int4*)kp;
        dst[0] = sp[0]; dst[1] = sp[1]; dst[2] = sp[2]; dst[3] = sp[3];
    }
    __syncthreads();
    int s = sblk * 256 + t;
    const half8* q8 = (const half8*)(Q + ((size_t)b * SS + s) * DD + h * 32);
    int cs = t & 31, ds = t >> 5;
    float sum = 0.f;
    #pragma unroll
    for (int v = 0; v < 4; ++v) {
        half8 qq = q8[v];
        #pragma unroll
        for (int j = 0; j < 8; ++j) {
            int e = v * 8 + j;
            sum += (float)qq[j] * (float)kt[(e * 8 + ds) * 32 + cs];
        }
    }
    dg[((size_t)b << 15) | ((size_t)h << 12) | s] = sum * 0.015625f;
}

// ---------------- attn_stat: att = resid + dg*V (stored); raw row sums -> st0 ----------------
__global__ __launch_bounds__(256) void attn_stat(const half_t* __restrict__ resid,
                                                 const half_t* __restrict__ V,
                                                 const float* __restrict__ dg,
                                                 half_t* __restrict__ att,
                                                 float2* __restrict__ st0,
                                                 float2* __restrict__ st1) {
    int wave = threadIdx.x >> 6, lane = threadIdx.x & 63;
    int row = blockIdx.x * 4 + wave;
    int b = row >> 12, s = row & (SS - 1);
    int h = lane >> 3;
    float dgv = dg[((size_t)b << 15) | ((size_t)h << 12) | s];
    size_t base = (size_t)row * DD + lane * 4;
    half4 rs4 = *(const half4*)(resid + base);
    half4 v4 = *(const half4*)(V + base);
    float a0 = (float)rs4[0] + dgv * (float)v4[0];
    float a1 = (float)rs4[1] + dgv * (float)v4[1];
    float a2 = (float)rs4[2] + dgv * (float)v4[2];
    float a3 = (float)rs4[3] + dgv * (float)v4[3];
    half4 at = { (half_t)a0, (half_t)a1, (half_t)a2, (half_t)a3 };
    *(half4*)(att + base) = at;
    float s1 = a0 + a1 + a2 + a3;
    float s2 = a0 * a0 + a1 * a1 + a2 * a2 + a3 * a3;
    #pragma unroll
    for (int m = 32; m; m >>= 1) {
        s1 += __shfl_xor(s1, m);
        s2 += __shfl_xor(s2, m);
    }
    if (lane == 0) {
        st0[row] = make_float2(s1, s2);
        st1[row] = make_float2(0.f, 0.f);
    }
}

// ---------------- final: LN of token 0 per batch -> fp32 out ----------------
__global__ __launch_bounds__(256) void final_ln_kernel(const half_t* __restrict__ cur,
                                                       float* __restrict__ out,
                                                       const float* __restrict__ gamma,
                                                       const float* __restrict__ beta) {
    int b = blockIdx.x;
    int d = threadIdx.x;
    float x = (float)cur[(size_t)b * SS * DD + d];
    float s1 = x, s2 = x * x;
    #pragma unroll
    for (int m = 32; m; m >>= 1) {
        s1 += __shfl_xor(s1, m);
        s2 += __shfl_xor(s2, m);
    }
    __shared__ float ls1[4], ls2[4];
    int wave = threadIdx.x >> 6, lane = threadIdx.x & 63;
    if (lane == 0) { ls1[wave] = s1; ls2[wave] = s2; }
    __syncthreads();
    float t1 = ls1[0] + ls1[1] + ls1[2] + ls1[3];
    float t2 = ls2[0] + ls2[1] + ls2[2] + ls2[3];
    float mu = t1 * (1.0f / DD);
    float var = t2 * (1.0f / DD) - mu * mu;
    float rs = rsqrtf(var + 1e-5f);
    out[(size_t)b * DD + d] = (x - mu) * rs * gamma[d] + beta[d];
}

extern "C" void kernel_launch(void* const* d_in, const int* in_sizes, int n_in,
                              void* d_out, int out_size, void* d_ws, size_t ws_size,
                              hipStream_t stream) {
    const float* x     = (const float*)d_in[0];
    const float* Wq    = (const float*)d_in[1];
    const float* Wk    = (const float*)d_in[2];
    const float* Wv    = (const float*)d_in[3];
    const float* W1    = (const float*)d_in[4];
    const float* b1    = (const float*)d_in[5];
    const float* W2    = (const float*)d_in[6];
    const float* b2    = (const float*)d_in[7];
    const float* gamma = (const float*)d_in[8];
    const float* beta  = (const float*)d_in[9];

    char* p = (char*)d_ws;
    half_t* x16  = (half_t*)p; p += (size_t)MTOT * DD * 2;
    half_t* cur  = (half_t*)p; p += (size_t)MTOT * DD * 2;
    half_t* att  = (half_t*)p; p += (size_t)MTOT * DD * 2;
    half_t* Qb   = (half_t*)p; p += (size_t)MTOT * DD * 2;
    half_t* Kb   = (half_t*)p; p += (size_t)MTOT * DD * 2;
    half_t* Vb   = (half_t*)p; p += (size_t)MTOT * DD * 2;
    half_t* m1   = (half_t*)p; p += (size_t)MTOT * DD * 2;
    float*  dgp  = (float*)p;  p += (size_t)BB * HH * SS * 4;
    float2* stA0 = (float2*)p; p += (size_t)MTOT * 8;
    float2* stA1 = (float2*)p; p += (size_t)MTOT * 8;
    float2* stB0 = (float2*)p; p += (size_t)MTOT * 8;
    float2* stB1 = (float2*)p; p += (size_t)MTOT * 8;
    half_t* Wall = (half_t*)p; p += (size_t)LL * 3 * 65536 * 2;
    half_t* W1h  = (half_t*)p; p += (size_t)LL * 65536 * 2;
    half_t* W2h  = (half_t*)p; p += (size_t)LL * 65536 * 2;
    float*  bqkv = (float*)p;  p += (size_t)LL * 3 * 256 * 4;
    float*  b1f  = (float*)p;  p += (size_t)LL * 256 * 4;
    float*  b2f  = (float*)p;  p += (size_t)LL * 256 * 4;

    prep_weights<<<LL * 5, 256, 0, stream>>>(Wq, Wk, Wv, W1, b1, W2, b2, gamma, beta,
                                             Wall, W1h, W2h, bqkv, b1f, b2f);
    cvt_x_stats<<<MTOT / 4, 256, 0, stream>>>(x, x16, stA0, stA1);

    const half_t* curin = x16;
    for (int l = 0; l < LL; ++l) {
        gemm64r<1, 0, 0><<<dim3(512, 2, 3), 256, 0, stream>>>(
            curin, stA0, stA1, Wall + (size_t)l * 3 * 65536, bqkv + l * 3 * 256,
            nullptr, Qb, Kb, Vb, nullptr, nullptr);
        diag_tiled<<<1024, 256, 0, stream>>>(Qb, Kb, dgp);
        attn_stat<<<MTOT / 4, 256, 0, stream>>>(curin, Vb, dgp, att, stB0, stB1);
        gemm64r<1, 1, 0><<<dim3(512, 2, 1), 256, 0, stream>>>(
            att, stB0, stB1, W1h + (size_t)l * 65536, b1f + l * 256,
            nullptr, m1, m1, m1, nullptr, nullptr);
        gemm64r<0, 2, 1><<<dim3(512, 2, 1), 256, 0, stream>>>(
            m1, nullptr, nullptr, W2h + (size_t)l * 65536, b2f + l * 256,
            att, cur, cur, cur, stA0, stA1);
        curin = cur;
    }
    final_ln_kernel<<<BB, 256, 0, stream>>>(cur, (float*)d_out, gamma, beta);
}

// Round 21
// 327.592 us; speedup vs baseline: 1.0336x; 1.0336x over previous
//
#include <hip/hip_runtime.h>
#include <hip/hip_bf16.h>
#include <hip/hip_fp16.h>

typedef _Float16 half_t;
typedef _Float16 half8 __attribute__((ext_vector_type(8)));
typedef _Float16 half4 __attribute__((ext_vector_type(4)));
typedef float f32x4 __attribute__((ext_vector_type(4)));

#define BB 8
#define SS 4096
#define DD 256
#define HH 8
#define LL 4
#define MTOT (BB*SS)   // 32768

__device__ inline float gelu_f(float v) { return 0.5f * v * (1.0f + erff(v * 0.70710678118f)); }
__device__ inline half8 splat8(half_t v) { return (half8){v, v, v, v, v, v, v, v}; }

// async global->LDS, 16B per lane; LDS dest linear in lane order.
__device__ __forceinline__ void gload16(const half_t* g, half_t* l) {
    __builtin_amdgcn_global_load_lds(
        (const __attribute__((address_space(1))) void*)g,
        (__attribute__((address_space(3))) void*)l, 16, 0, 0);
}

// ---------------- weight prep: fold LN gamma/beta into weights ----------------
__global__ __launch_bounds__(256) void prep_weights(
    const float* __restrict__ Wq, const float* __restrict__ Wk, const float* __restrict__ Wv,
    const float* __restrict__ W1, const float* __restrict__ b1,
    const float* __restrict__ W2, const float* __restrict__ b2,
    const float* __restrict__ gamma, const float* __restrict__ beta,
    half_t* __restrict__ Wall, half_t* __restrict__ W1h, half_t* __restrict__ W2h,
    float* __restrict__ bqkv, float* __restrict__ b1f, float* __restrict__ b2f)
{
    int blk = blockIdx.x;            // 20 blocks: l*5 + type
    int l = blk / 5, type = blk % 5;
    int o = threadIdx.x;
    const float* src = (type == 0 ? Wq : type == 1 ? Wk : type == 2 ? Wv : type == 3 ? W1 : W2)
                       + ((size_t)l * 256 + o) * 256;
    half_t* dsth = (type < 3) ? Wall + ((size_t)(l * 3 + type) * 256 + o) * 256
                 : (type == 3) ? W1h + ((size_t)l * 256 + o) * 256
                               : W2h + ((size_t)l * 256 + o) * 256;
    float acc = 0.f;
    for (int d4 = 0; d4 < 64; ++d4) {
        float4 w = *(const float4*)(src + d4 * 4);
        half4 hv;
        if (type == 4) {
            hv = half4{ (half_t)w.x, (half_t)w.y, (half_t)w.z, (half_t)w.w };
        } else {
            float4 g = *(const float4*)(gamma + d4 * 4);
            float4 bt = *(const float4*)(beta + d4 * 4);
            acc += w.x * bt.x + w.y * bt.y + w.z * bt.z + w.w * bt.w;
            hv = half4{ (half_t)(w.x * g.x), (half_t)(w.y * g.y), (half_t)(w.z * g.z), (half_t)(w.w * g.w) };
        }
        *(half4*)(dsth + d4 * 4) = hv;
    }
    if (type < 3) bqkv[(l * 3 + type) * 256 + o] = acc;
    else if (type == 3) b1f[l * 256 + o] = b1[l * 256 + o] + acc;
    else b2f[l * 256 + o] = b2[l * 256 + o];
}

// ---------------- x fp32 -> fp16 + raw row sums (partial-stats format) ----------------
__global__ __launch_bounds__(256) void cvt_x_stats(const float* __restrict__ in,
                                                   half_t* __restrict__ out,
                                                   float2* __restrict__ st0,
                                                   float2* __restrict__ st1) {
    int wave = threadIdx.x >> 6, lane = threadIdx.x & 63;
    int row = blockIdx.x * 4 + wave;
    const float* ip = in + (size_t)row * DD + lane * 4;
    float4 v = *(const float4*)ip;
    half4 h = { (half_t)v.x, (half_t)v.y, (half_t)v.z, (half_t)v.w };
    *(half4*)(out + (size_t)row * DD + lane * 4) = h;
    float s1 = v.x + v.y + v.z + v.w;
    float s2 = v.x * v.x + v.y * v.y + v.z * v.z + v.w * v.w;
    #pragma unroll
    for (int m = 32; m; m >>= 1) {
        s1 += __shfl_xor(s1, m);
        s2 += __shfl_xor(s2, m);
    }
    if (lane == 0) {
        st0[row] = make_float2(s1, s2);
        st1[row] = make_float2(0.f, 0.f);
    }
}

// ---------------- XCD-aware bijective remap (gridDim.x % 8 == 0) ----------------
__device__ inline void xcd_remap(int& bx, int& by, int& bz) {
    int lin = blockIdx.x + gridDim.x * (blockIdx.y + gridDim.y * blockIdx.z);
    int nyz = gridDim.y * gridDim.z;
    int xcd = lin & 7;
    int slot = lin >> 3;
    int yz = slot % nyz;
    int xi = slot / nyz;
    bx = xcd + 8 * xi;
    by = yz % gridDim.y;
    bz = yz / gridDim.y;
}

// ---------------- 128x128 GEMM, BK=64, 4 waves of 64x64, SINGLE-buffer (QKV) ------------
template<int NORM, int EPI, int STATS>
__global__ __launch_bounds__(256) void gemm128(const half_t* __restrict__ A,
                                               const float2* __restrict__ st0,
                                               const float2* __restrict__ st1,
                                               const half_t* __restrict__ Wbase,
                                               const float* __restrict__ biasBase,
                                               const half_t* __restrict__ resid,
                                               half_t* __restrict__ o0,
                                               half_t* __restrict__ o1,
                                               half_t* __restrict__ o2,
                                               float2* __restrict__ outSt0,
                                               float2* __restrict__ outSt1) {
    const int t = threadIdx.x, lane = t & 63, wavei = t >> 6;
    const int wm = wavei >> 1, wn = wavei & 1, r = lane & 15, g = lane >> 4;
    int bx, by, bz;
    xcd_remap(bx, by, bz);
    const int row0 = bx * 128, col0 = by * 128;
    const half_t* W = Wbase + (size_t)bz * 65536;
    const float* bias = biasBase + bz * 256;
    half_t* outp = (bz == 0) ? o0 : ((bz == 1) ? o1 : o2);

    __shared__ __align__(16) half_t lds[16384];   // A [0,8192), B [8192,16384)

    const half_t* Ag = A + (size_t)row0 * DD;
    const half_t* Wg = W + (size_t)col0 * DD;

    half8 sA[4], bA[4];
    if (NORM) {
        #pragma unroll
        for (int mt = 0; mt < 4; ++mt) {
            int row = row0 + wm * 64 + mt * 16 + r;
            float2 p0 = st0[row], p1 = st1[row];
            float s1 = p0.x + p1.x, s2 = p0.y + p1.y;
            float mu = s1 * (1.0f / DD);
            float var = s2 * (1.0f / DD) - mu * mu;
            float rs = rsqrtf(var + 1e-5f);
            sA[mt] = splat8((half_t)rs);
            bA[mt] = splat8((half_t)(-mu * rs));
        }
    }

    int rowS[4], chS[4];
    #pragma unroll
    for (int i = 0; i < 4; ++i) {
        int G = i * 256 + t;
        rowS[i] = G >> 3;
        chS[i] = ((G & 7) ^ (rowS[i] & 7)) * 8;
    }

    f32x4 acc[4][4];
    #pragma unroll
    for (int i = 0; i < 4; ++i)
        #pragma unroll
        for (int j = 0; j < 4; ++j) acc[i][j] = (f32x4){0.f, 0.f, 0.f, 0.f};

    #pragma unroll
    for (int stp = 0; stp < 4; ++stp) {
        int kk = stp * 64;
        #pragma unroll
        for (int i = 0; i < 4; ++i) {
            int G = i * 256 + t;
            gload16(Ag + (size_t)rowS[i] * DD + kk + chS[i], &lds[G * 8]);
            gload16(Wg + (size_t)rowS[i] * DD + kk + chS[i], &lds[8192 + G * 8]);
        }
        __syncthreads();
        #pragma unroll
        for (int ks = 0; ks < 2; ++ks) {
            half8 af[4], bf[4];
            #pragma unroll
            for (int mt = 0; mt < 4; ++mt) {
                int rw = wm * 64 + mt * 16 + r;
                int cc = (ks * 4 + g) ^ (rw & 7);
                half8 raw = *(const half8*)&lds[rw * 64 + cc * 8];
                af[mt] = NORM ? (half8)(raw * sA[mt] + bA[mt]) : raw;
            }
            #pragma unroll
            for (int nt = 0; nt < 4; ++nt) {
                int rw = wn * 64 + nt * 16 + r;
                int cc = (ks * 4 + g) ^ (rw & 7);
                bf[nt] = *(const half8*)&lds[8192 + rw * 64 + cc * 8];
            }
            #pragma unroll
            for (int mt = 0; mt < 4; ++mt)
                #pragma unroll
                for (int nt = 0; nt < 4; ++nt)
                    acc[mt][nt] = __builtin_amdgcn_mfma_f32_16x16x32_f16(af[mt], bf[nt], acc[mt][nt], 0, 0, 0);
        }
        __syncthreads();
    }

    half_t* ldsT = &lds[0];
    #pragma unroll
    for (int mt = 0; mt < 4; ++mt) {
        #pragma unroll
        for (int nt = 0; nt < 4; ++nt) {
            int colL = wn * 64 + nt * 16 + r;
            float bv = bias[col0 + colL];
            #pragma unroll
            for (int j = 0; j < 4; ++j) {
                int rowL = wm * 64 + mt * 16 + g * 4 + j;
                float v = acc[mt][nt][j] + bv;
                if (EPI != 0) v = gelu_f(v);
                ldsT[rowL * 128 + (colL ^ ((rowL & 12) << 2))] = (half_t)v;
            }
        }
    }
    __syncthreads();
    const int l15 = lane & 15, lg = lane >> 4;
    float2* outSt = (by == 0) ? outSt0 : outSt1;
    #pragma unroll
    for (int i = 0; i < 8; ++i) {
        int rowL = wavei * 32 + lg * 8 + i;
        int colL = l15 * 8;
        half8 v = *(const half8*)&ldsT[rowL * 128 + (colL ^ ((rowL & 12) << 2))];
        size_t off = (size_t)(row0 + rowL) * DD + col0 + colL;
        if (EPI == 2) {
            half8 rsd = *(const half8*)&resid[off];
            #pragma unroll
            for (int q = 0; q < 8; ++q) v[q] = (half_t)((float)v[q] + (float)rsd[q]);
        }
        *(half8*)&outp[off] = v;
        if (STATS) {
            float s1 = 0.f, s2 = 0.f;
            #pragma unroll
            for (int q = 0; q < 8; ++q) { float f = (float)v[q]; s1 += f; s2 += f * f; }
            #pragma unroll
            for (int m = 1; m <= 8; m <<= 1) {
                s1 += __shfl_xor(s1, m);
                s2 += __shfl_xor(s2, m);
            }
            if (l15 == 0) outSt[row0 + rowL] = make_float2(s1, s2);
        }
    }
}

// ---------------- 64x128 GEMM (FFN): BM=64, single-buffer 24KB -> 4 blocks/CU at grid 1024
template<int NORM, int EPI, int STATS>
__global__ __launch_bounds__(256) void gemm64r(const half_t* __restrict__ A,
                                               const float2* __restrict__ st0,
                                               const float2* __restrict__ st1,
                                               const half_t* __restrict__ W,
                                               const float* __restrict__ bias,
                                               const half_t* __restrict__ resid,
                                               half_t* __restrict__ outp,
                                               float2* __restrict__ outSt0,
                                               float2* __restrict__ outSt1) {
    const int t = threadIdx.x, lane = t & 63, wavei = t >> 6;
    const int wm = wavei >> 1, wn = wavei & 1, r = lane & 15, g = lane >> 4;
    int bx, by, bz;
    xcd_remap(bx, by, bz);
    const int row0 = bx * 64, col0 = by * 128;

    __shared__ __align__(16) half_t lds[12288];   // A [0,4096), W [4096,12288)

    const half_t* Ag = A + (size_t)row0 * DD;
    const half_t* Wg = W + (size_t)col0 * DD;

    half8 sA[2], bA[2];
    if (NORM) {
        #pragma unroll
        for (int mt = 0; mt < 2; ++mt) {
            int row = row0 + wm * 32 + mt * 16 + r;
            float2 p0 = st0[row], p1 = st1[row];
            float s1 = p0.x + p1.x, s2 = p0.y + p1.y;
            float mu = s1 * (1.0f / DD);
            float var = s2 * (1.0f / DD) - mu * mu;
            float rs = rsqrtf(var + 1e-5f);
            sA[mt] = splat8((half_t)rs);
            bA[mt] = splat8((half_t)(-mu * rs));
        }
    }

    int rwA[2], chA[2], rwW[4], chW[4];
    #pragma unroll
    for (int i = 0; i < 2; ++i) {
        int G = i * 256 + t;
        rwA[i] = G >> 3;
        chA[i] = ((G & 7) ^ (rwA[i] & 7)) * 8;
    }
    #pragma unroll
    for (int i = 0; i < 4; ++i) {
        int G = i * 256 + t;
        rwW[i] = G >> 3;
        chW[i] = ((G & 7) ^ (rwW[i] & 7)) * 8;
    }

    f32x4 acc[2][4];
    #pragma unroll
    for (int i = 0; i < 2; ++i)
        #pragma unroll
        for (int j = 0; j < 4; ++j) acc[i][j] = (f32x4){0.f, 0.f, 0.f, 0.f};

    #pragma unroll
    for (int stp = 0; stp < 4; ++stp) {
        int kk = stp * 64;
        #pragma unroll
        for (int i = 0; i < 2; ++i)
            gload16(Ag + (size_t)rwA[i] * DD + kk + chA[i], &lds[(i * 256 + t) * 8]);
        #pragma unroll
        for (int i = 0; i < 4; ++i)
            gload16(Wg + (size_t)rwW[i] * DD + kk + chW[i], &lds[4096 + (i * 256 + t) * 8]);
        __syncthreads();
        #pragma unroll
        for (int ks = 0; ks < 2; ++ks) {
            half8 af[2], bf[4];
            #pragma unroll
            for (int mt = 0; mt < 2; ++mt) {
                int rw = wm * 32 + mt * 16 + r;
                int cc = (ks * 4 + g) ^ (rw & 7);
                half8 raw = *(const half8*)&lds[rw * 64 + cc * 8];
                af[mt] = NORM ? (half8)(raw * sA[mt] + bA[mt]) : raw;
            }
            #pragma unroll
            for (int nt = 0; nt < 4; ++nt) {
                int rw = wn * 64 + nt * 16 + r;
                int cc = (ks * 4 + g) ^ (rw & 7);
                bf[nt] = *(const half8*)&lds[4096 + rw * 64 + cc * 8];
            }
            #pragma unroll
            for (int mt = 0; mt < 2; ++mt)
                #pragma unroll
                for (int nt = 0; nt < 4; ++nt)
                    acc[mt][nt] = __builtin_amdgcn_mfma_f32_16x16x32_f16(af[mt], bf[nt], acc[mt][nt], 0, 0, 0);
        }
        __syncthreads();
    }

    // epilogue: 64x128 tile (16KB) into lds[0..8191]
    half_t* ldsT = &lds[0];
    #pragma unroll
    for (int mt = 0; mt < 2; ++mt) {
        #pragma unroll
        for (int nt = 0; nt < 4; ++nt) {
            int colL = wn * 64 + nt * 16 + r;
            float bv = bias[col0 + colL];
            #pragma unroll
            for (int j = 0; j < 4; ++j) {
                int rowL = wm * 32 + mt * 16 + g * 4 + j;
                float v = acc[mt][nt][j] + bv;
                if (EPI != 0) v = gelu_f(v);
                ldsT[rowL * 128 + (colL ^ ((rowL & 12) << 2))] = (half_t)v;
            }
        }
    }
    __syncthreads();
    float2* outSt = (by == 0) ? outSt0 : outSt1;
    #pragma unroll
    for (int i = 0; i < 4; ++i) {
        int G = i * 256 + t;
        int rowL = G >> 4;
        int colL = (G & 15) * 8;
        half8 v = *(const half8*)&ldsT[rowL * 128 + (colL ^ ((rowL & 12) << 2))];
        size_t off = (size_t)(row0 + rowL) * DD + col0 + colL;
        if (EPI == 2) {
            half8 rsd = *(const half8*)&resid[off];
            #pragma unroll
            for (int q = 0; q < 8; ++q) v[q] = (half_t)((float)v[q] + (float)rsd[q]);
        }
        *(half8*)&outp[off] = v;
        if (STATS) {
            float s1 = 0.f, s2 = 0.f;
            #pragma unroll
            for (int q = 0; q < 8; ++q) { float f = (float)v[q]; s1 += f; s2 += f * f; }
            #pragma unroll
            for (int m = 1; m <= 8; m <<= 1) {
                s1 += __shfl_xor(s1, m);
                s2 += __shfl_xor(s2, m);
            }
            if ((t & 15) == 0) outSt[row0 + rowL] = make_float2(s1, s2);
        }
    }
}

// ---------------- diag: LDS-tiled ----------------
__global__ __launch_bounds__(256) void diag_tiled(const half_t* __restrict__ Q,
                                                  const half_t* __restrict__ K,
                                                  float* __restrict__ dg) {
    int blk = blockIdx.x;                 // b*128 + h*16 + sblk
    int sblk = blk & 15, h = (blk >> 4) & 7, b = blk >> 7;
    int t = threadIdx.x;
    __shared__ __align__(16) half_t kt[256 * 32];   // 16 KB
    int r0b = sblk * 8;
    {
        int e = t >> 3, del = t & 7;
        const half_t* kp = K + ((size_t)b * SS + e * 128 + r0b + del) * DD + h * 32;
        int4* dst = (int4*)&kt[t * 32];
        const int4* sp = (const int4*)kp;
        dst[0] = sp[0]; dst[1] = sp[1]; dst[2] = sp[2]; dst[3] = sp[3];
    }
    __syncthreads();
    int s = sblk * 256 + t;
    const half8* q8 = (const half8*)(Q + ((size_t)b * SS + s) * DD + h * 32);
    int cs = t & 31, ds = t >> 5;
    float sum = 0.f;
    #pragma unroll
    for (int v = 0; v < 4; ++v) {
        half8 qq = q8[v];
        #pragma unroll
        for (int j = 0; j < 8; ++j) {
            int e = v * 8 + j;
            sum += (float)qq[j] * (float)kt[(e * 8 + ds) * 32 + cs];
        }
    }
    dg[((size_t)b << 15) | ((size_t)h << 12) | s] = sum * 0.015625f;
}

// ---------------- attn_stat: att = resid + dg*V (stored); raw row sums -> st0 ----------------
__global__ __launch_bounds__(256) void attn_stat(const half_t* __restrict__ resid,
                                                 const half_t* __restrict__ V,
                                                 const float* __restrict__ dg,
                                                 half_t* __restrict__ att,
                                                 float2* __restrict__ st0,
                                                 float2* __restrict__ st1) {
    int wave = threadIdx.x >> 6, lane = threadIdx.x & 63;
    int row = blockIdx.x * 4 + wave;
    int b = row >> 12, s = row & (SS - 1);
    int h = lane >> 3;
    float dgv = dg[((size_t)b << 15) | ((size_t)h << 12) | s];
    size_t base = (size_t)row * DD + lane * 4;
    half4 rs4 = *(const half4*)(resid + base);
    half4 v4 = *(const half4*)(V + base);
    float a0 = (float)rs4[0] + dgv * (float)v4[0];
    float a1 = (float)rs4[1] + dgv * (float)v4[1];
    float a2 = (float)rs4[2] + dgv * (float)v4[2];
    float a3 = (float)rs4[3] + dgv * (float)v4[3];
    half4 at = { (half_t)a0, (half_t)a1, (half_t)a2, (half_t)a3 };
    *(half4*)(att + base) = at;
    float s1 = a0 + a1 + a2 + a3;
    float s2 = a0 * a0 + a1 * a1 + a2 * a2 + a3 * a3;
    #pragma unroll
    for (int m = 32; m; m >>= 1) {
        s1 += __shfl_xor(s1, m);
        s2 += __shfl_xor(s2, m);
    }
    if (lane == 0) {
        st0[row] = make_float2(s1, s2);
        st1[row] = make_float2(0.f, 0.f);
    }
}

// ---------------- final: LN of token 0 per batch -> fp32 out ----------------
__global__ __launch_bounds__(256) void final_ln_kernel(const half_t* __restrict__ cur,
                                                       float* __restrict__ out,
                                                       const float* __restrict__ gamma,
                                                       const float* __restrict__ beta) {
    int b = blockIdx.x;
    int d = threadIdx.x;
    float x = (float)cur[(size_t)b * SS * DD + d];
    float s1 = x, s2 = x * x;
    #pragma unroll
    for (int m = 32; m; m >>= 1) {
        s1 += __shfl_xor(s1, m);
        s2 += __shfl_xor(s2, m);
    }
    __shared__ float ls1[4], ls2[4];
    int wave = threadIdx.x >> 6, lane = threadIdx.x & 63;
    if (lane == 0) { ls1[wave] = s1; ls2[wave] = s2; }
    __syncthreads();
    float t1 = ls1[0] + ls1[1] + ls1[2] + ls1[3];
    float t2 = ls2[0] + ls2[1] + ls2[2] + ls2[3];
    float mu = t1 * (1.0f / DD);
    float var = t2 * (1.0f / DD) - mu * mu;
    float rs = rsqrtf(var + 1e-5f);
    out[(size_t)b * DD + d] = (x - mu) * rs * gamma[d] + beta[d];
}

extern "C" void kernel_launch(void* const* d_in, const int* in_sizes, int n_in,
                              void* d_out, int out_size, void* d_ws, size_t ws_size,
                              hipStream_t stream) {
    const float* x     = (const float*)d_in[0];
    const float* Wq    = (const float*)d_in[1];
    const float* Wk    = (const float*)d_in[2];
    const float* Wv    = (const float*)d_in[3];
    const float* W1    = (const float*)d_in[4];
    const float* b1    = (const float*)d_in[5];
    const float* W2    = (const float*)d_in[6];
    const float* b2    = (const float*)d_in[7];
    const float* gamma = (const float*)d_in[8];
    const float* beta  = (const float*)d_in[9];

    char* p = (char*)d_ws;
    half_t* x16  = (half_t*)p; p += (size_t)MTOT * DD * 2;
    half_t* cur  = (half_t*)p; p += (size_t)MTOT * DD * 2;
    half_t* att  = (half_t*)p; p += (size_t)MTOT * DD * 2;
    half_t* Qb   = (half_t*)p; p += (size_t)MTOT * DD * 2;
    half_t* Kb   = (half_t*)p; p += (size_t)MTOT * DD * 2;
    half_t* Vb   = (half_t*)p; p += (size_t)MTOT * DD * 2;
    half_t* m1   = (half_t*)p; p += (size_t)MTOT * DD * 2;
    float*  dgp  = (float*)p;  p += (size_t)BB * HH * SS * 4;
    float2* stA0 = (float2*)p; p += (size_t)MTOT * 8;
    float2* stA1 = (float2*)p; p += (size_t)MTOT * 8;
    float2* stB0 = (float2*)p; p += (size_t)MTOT * 8;
    float2* stB1 = (float2*)p; p += (size_t)MTOT * 8;
    half_t* Wall = (half_t*)p; p += (size_t)LL * 3 * 65536 * 2;
    half_t* W1h  = (half_t*)p; p += (size_t)LL * 65536 * 2;
    half_t* W2h  = (half_t*)p; p += (size_t)LL * 65536 * 2;
    float*  bqkv = (float*)p;  p += (size_t)LL * 3 * 256 * 4;
    float*  b1f  = (float*)p;  p += (size_t)LL * 256 * 4;
    float*  b2f  = (float*)p;  p += (size_t)LL * 256 * 4;

    prep_weights<<<LL * 5, 256, 0, stream>>>(Wq, Wk, Wv, W1, b1, W2, b2, gamma, beta,
                                             Wall, W1h, W2h, bqkv, b1f, b2f);
    cvt_x_stats<<<MTOT / 4, 256, 0, stream>>>(x, x16, stA0, stA1);

    const half_t* curin = x16;
    for (int l = 0; l < LL; ++l) {
        gemm128<1, 0, 0><<<dim3(256, 2, 3), 256, 0, stream>>>(
            curin, stA0, stA1, Wall + (size_t)l * 3 * 65536, bqkv + l * 3 * 256,
            nullptr, Qb, Kb, Vb, nullptr, nullptr);
        diag_tiled<<<1024, 256, 0, stream>>>(Qb, Kb, dgp);
        attn_stat<<<MTOT / 4, 256, 0, stream>>>(curin, Vb, dgp, att, stB0, stB1);
        gemm64r<1, 1, 0><<<dim3(512, 2, 1), 256, 0, stream>>>(
            att, stB0, stB1, W1h + (size_t)l * 65536, b1f + l * 256,
            nullptr, m1, nullptr, nullptr);
        gemm64r<0, 2, 1><<<dim3(512, 2, 1), 256, 0, stream>>>(
            m1, nullptr, nullptr, W2h + (size_t)l * 65536, b2f + l * 256,
            att, cur, stA0, stA1);
        curin = cur;
    }
    final_ln_kernel<<<BB, 256, 0, stream>>>(cur, (float*)d_out, gamma, beta);
}